// Round 3
// baseline (278259.766 us; speedup 1.0000x reference)
//
#include <hip/hip_runtime.h>
#include <hip/hip_bf16.h>

// RNN: B=4096, T=1024, H=40, combined K=41.
// Correctness-anchor design:
//  - one wave (64 threads) per block, one batch element per lane
//  - hidden[40] and act[80] in VGPRs, weights broadcast from LDS
//  - NO inter-wave cooperation, NO barriers in the t-loop (race-proof)
//  - runtime dtype autodetect (bf16 vs fp32 harness buffers)

#define B_SZ 4096
#define T_SZ 1024
#define HID  40

__device__ __forceinline__ float ldw(const void* p, int i, bool bf) {
  if (bf) {
    unsigned int u = ((unsigned int)((const unsigned short*)p)[i]) << 16;
    union { unsigned int u; float f; } c; c.u = u;
    return c.f;
  }
  return ((const float*)p)[i];
}

__global__ __launch_bounds__(64)
void rnn_kernel(const void* __restrict__ inp,
                const void* __restrict__ h2h_w1, const void* __restrict__ h2h_b1,
                const void* __restrict__ h2h_w2, const void* __restrict__ h2h_b2,
                const void* __restrict__ h2o_w1, const void* __restrict__ h2o_b1,
                const void* __restrict__ h2o_w2, const void* __restrict__ h2o_b2,
                void* __restrict__ out) {
  // Untransposed weight copies (fp32) — row j contiguous for vector ds_reads.
  __shared__ float sW1[80][44];  // rows 0..39 = h2h_w1[j][0..40], 40..79 = h2o_w1[j-40][0..40]
  __shared__ float sW2[40][40];  // h2h_w2[r][n]
  __shared__ float sW2o[40];     // h2o_w2[0][n]
  __shared__ float sB1[80];      // h2h_b1 ++ h2o_b1
  __shared__ float sB2[40];      // h2h_b2

  const int tid = threadIdx.x;

  // ---- dtype autodetect (uniform across all threads) ----
  // True bf16 weights satisfy |w| <= 1/sqrt(41) ~= 0.156. fp32 data read as
  // bf16 halfwords has random exponents in the even halfwords -> exceeds 0.2
  // with overwhelming probability.
  bool bf = true;
  {
    const unsigned short* p = (const unsigned short*)h2h_w1;
    for (int i = 0; i < 64; ++i) {
      unsigned int u = ((unsigned int)p[i]) << 16;
      union { unsigned int u; float f; } c; c.u = u;
      if (!(fabsf(c.f) <= 0.2f)) bf = false;
    }
  }

  // ---- stage weights to LDS (direct copy, no transpose) ----
  for (int idx = tid; idx < 80 * 41; idx += 64) {
    int j = idx / 41, k = idx % 41;
    sW1[j][k] = (j < HID) ? ldw(h2h_w1, j * 41 + k, bf)
                          : ldw(h2o_w1, (j - HID) * 41 + k, bf);
  }
  for (int idx = tid; idx < HID * HID; idx += 64)
    sW2[idx / HID][idx % HID] = ldw(h2h_w2, idx, bf);
  for (int j = tid; j < HID; j += 64) {
    sW2o[j] = ldw(h2o_w2, j, bf);
    sB2[j]  = ldw(h2h_b2, j, bf);
  }
  for (int j = tid; j < 80; j += 64)
    sB1[j] = (j < HID) ? ldw(h2h_b1, j, bf) : ldw(h2o_b1, j - HID, bf);
  const float bias2o = ldw(h2o_b2, 0, bf);
  __syncthreads();  // the only barrier; LDS is read-only hereafter

  const int b = blockIdx.x * 64 + tid;
  const size_t base = (size_t)b * T_SZ;

  float h[HID];
#pragma unroll
  for (int i = 0; i < HID; ++i) h[i] = 0.f;

  for (int t = 0; t < T_SZ; ++t) {
    float u;
    if (bf) u = ldw(inp, (int)(base + t), true);
    else    u = ((const float*)inp)[base + t];

    // ---- layer 1: 80 neurons, combined = [u, h[0..39]] ----
    float act[80];
#pragma unroll
    for (int j = 0; j < 80; ++j) {
      float a = fmaf(u, sW1[j][0], sB1[j]);
#pragma unroll
      for (int k = 0; k < HID; ++k) a = fmaf(h[k], sW1[j][1 + k], a);
      act[j] = a > 0.f ? a : 0.01f * a;  // LeakyReLU(0.01)
    }

    // ---- layer 2a: hidden_new (overwrite h; layer 1 is done with it) ----
#pragma unroll
    for (int r = 0; r < HID; ++r) {
      float a = sB2[r];
#pragma unroll
      for (int j = 0; j < HID; ++j) a = fmaf(act[j], sW2[r][j], a);
      h[r] = a;
    }

    // ---- layer 2b: output scalar from o-activations ----
    float o = bias2o;
#pragma unroll
    for (int j = 0; j < HID; ++j) o = fmaf(act[HID + j], sW2o[j], o);

    if (bf) ((__hip_bfloat16*)out)[base + t] = __float2bfloat16(o);
    else    ((float*)out)[base + t] = o;
  }
}

extern "C" void kernel_launch(void* const* d_in, const int* in_sizes, int n_in,
                              void* d_out, int out_size, void* d_ws, size_t ws_size,
                              hipStream_t stream) {
  (void)in_sizes; (void)n_in; (void)out_size; (void)d_ws; (void)ws_size;
  rnn_kernel<<<dim3(B_SZ / 64), dim3(64), 0, stream>>>(
      d_in[0], d_in[1], d_in[2], d_in[3], d_in[4],
      d_in[5], d_in[6], d_in[7], d_in[8], d_out);
}

// Round 4
// 2038.300 us; speedup vs baseline: 136.5156x; 136.5156x over previous
//
#include <hip/hip_runtime.h>
#include <hip/hip_bf16.h>

// RNN: B=4096, T=1024, H=40, combined K=41. bf16 I/O, fp32 compute.
// Cooperative full-chip design:
//   256 blocks x 512 threads (8 waves). Block owns 16 batch elems.
//   lane: el = lane&15 (batch elem), sub = lane>>4; slot = wv*4+sub (0..31).
//   Phase A: 80 layer-1 neurons over 32 slots (3 for slots 0..15, 2 for 16..31;
//            wave-uniform since slot<16 <=> wv<4).
//   Phase B: 41 rows (40 hidden + 1 output) over 32 slots (2 for slots 0..8's
//            rows 0..17, 1 each for slots 9..31 -> rows 18..40; row 40 = output).
//   2 barriers per timestep; all weights staged fp32 in LDS (round-3-proven code).
//   Max ~50 live floats per thread -> no spill (round-3 killer).

#define B_SZ 4096
#define T_SZ 1024
#define HID  40

__device__ __forceinline__ float ldw(const void* p, int i, bool bf) {
  if (bf) {
    unsigned int u = ((unsigned int)((const unsigned short*)p)[i]) << 16;
    union { unsigned int u; float f; } c; c.u = u;
    return c.f;
  }
  return ((const float*)p)[i];
}

__global__ __launch_bounds__(512, 2)
void rnn_kernel(const void* __restrict__ inp,
                const void* __restrict__ h2h_w1, const void* __restrict__ h2h_b1,
                const void* __restrict__ h2h_w2, const void* __restrict__ h2h_b2,
                const void* __restrict__ h2o_w1, const void* __restrict__ h2o_b1,
                const void* __restrict__ h2o_w2, const void* __restrict__ h2o_b2,
                void* __restrict__ out) {
  __shared__ float sW1[80][44];   // [j][k]: k=0 -> u, k=1..40 -> h[k-1], 41..43 = 0 pad
  __shared__ float sW2[40][40];   // h2h_w2[r][j]
  __shared__ float sW2o[40];      // h2o_w2[0][j]
  __shared__ float sB1[80];       // h2h_b1 ++ h2o_b1
  __shared__ float sB2[40];       // h2h_b2
  __shared__ float sAct[80][16];  // [j][el]; j<40: a (h2h), j>=40: o-path acts
  __shared__ float sH[HID][16];   // [k][el] hidden state

  const int tid  = threadIdx.x;
  const int lane = tid & 63;
  const int wv   = tid >> 6;        // 0..7
  const int el   = lane & 15;       // batch elem within tile
  const int sub  = lane >> 4;       // 0..3
  const int slot = wv * 4 + sub;    // 0..31

  // ---- dtype autodetect (uniform) — proven in round 3 ----
  bool bf = true;
  {
    const unsigned short* p = (const unsigned short*)h2h_w1;
    for (int i = 0; i < 64; ++i) {
      unsigned int u = ((unsigned int)p[i]) << 16;
      union { unsigned int u; float f; } c; c.u = u;
      if (!(fabsf(c.f) <= 0.2f)) bf = false;
    }
  }

  // ---- stage weights to LDS (round-3-proven mappings, +pad) ----
  for (int idx = tid; idx < 80 * 44; idx += 512) {
    int j = idx / 44, k = idx % 44;
    float v = 0.f;
    if (k < 41)
      v = (j < HID) ? ldw(h2h_w1, j * 41 + k, bf)
                    : ldw(h2o_w1, (j - HID) * 41 + k, bf);
    sW1[j][k] = v;
  }
  for (int idx = tid; idx < HID * HID; idx += 512)
    sW2[idx / HID][idx % HID] = ldw(h2h_w2, idx, bf);
  for (int j = tid; j < HID; j += 512) {
    sW2o[j] = ldw(h2o_w2, j, bf);
    sB2[j]  = ldw(h2h_b2, j, bf);
  }
  for (int j = tid; j < 80; j += 512)
    sB1[j] = (j < HID) ? ldw(h2h_b1, j, bf) : ldw(h2o_b1, j - HID, bf);
  for (int idx = tid; idx < HID * 16; idx += 512)
    ((float*)sH)[idx] = 0.f;
  const float bias2o = ldw(h2o_b2, 0, bf);
  __syncthreads();

  const int b = blockIdx.x * 16 + el;
  const size_t base = (size_t)b * T_SZ;

  // Phase-A assignment: slots 0..15 -> acts {3s,3s+1,3s+2}; 16..31 -> {48+2(s-16), ...+1}
  const int a0 = (slot < 16) ? slot * 3 : 48 + (slot - 16) * 2;
  const int na = (slot < 16) ? 3 : 2;          // wave-uniform (slot<16 <=> wv<4)
  // Phase-B assignment: slots 0..8 -> rows {2s,2s+1}; slots 9..31 -> row 18+(s-9)
  const int r0 = (slot < 9) ? 2 * slot : 18 + (slot - 9);   // slot 31 -> row 40 (output)
  const int nr = (slot < 9) ? 2 : 1;

  for (int t = 0; t < T_SZ; ++t) {
    // ---------- Phase A: layer 1 ----------
    float u;
    if (bf) u = ldw(inp, (int)(base + t), true);
    else    u = ((const float*)inp)[base + t];

    float h[HID];
#pragma unroll
    for (int k = 0; k < HID; ++k) h[k] = sH[k][el];

#pragma unroll
    for (int q = 0; q < 3; ++q) {
      if (q < na) {
        const int j = a0 + q;
        float a = fmaf(u, sW1[j][0], sB1[j]);
#pragma unroll
        for (int k = 0; k < HID; ++k) a = fmaf(h[k], sW1[j][1 + k], a);
        a = a > 0.f ? a : 0.01f * a;       // LeakyReLU(0.01)
        sAct[j][el] = a;
      }
    }
    __syncthreads();  // sAct visible; all sH reads complete

    // ---------- Phase B: layer 2 ----------
    if (r0 < HID) {
      float av[HID];
#pragma unroll
      for (int j = 0; j < HID; ++j) av[j] = sAct[j][el];  // a-path acts
#pragma unroll
      for (int q = 0; q < 2; ++q) {
        if (q < nr) {
          const int r = r0 + q;
          float a = sB2[r];
#pragma unroll
          for (int j = 0; j < HID; ++j) a = fmaf(av[j], sW2[r][j], a);
          sH[r][el] = a;                    // new hidden
        }
      }
    } else {
      float a = bias2o;                     // row 40: output scalar
#pragma unroll
      for (int j = 0; j < HID; ++j) a = fmaf(sAct[HID + j][el], sW2o[j], a);
      if (bf) ((__hip_bfloat16*)out)[base + t] = __float2bfloat16(a);
      else    ((float*)out)[base + t] = a;
    }
    __syncthreads();  // sH update + sAct reads complete before next step
  }
}

extern "C" void kernel_launch(void* const* d_in, const int* in_sizes, int n_in,
                              void* d_out, int out_size, void* d_ws, size_t ws_size,
                              hipStream_t stream) {
  (void)in_sizes; (void)n_in; (void)out_size; (void)d_ws; (void)ws_size;
  rnn_kernel<<<dim3(B_SZ / 16), dim3(512), 0, stream>>>(
      d_in[0], d_in[1], d_in[2], d_in[3], d_in[4],
      d_in[5], d_in[6], d_in[7], d_in[8], d_out);
}

// Round 5
// 2026.609 us; speedup vs baseline: 137.3031x; 1.0058x over previous
//
#include <hip/hip_runtime.h>
#include <hip/hip_bf16.h>

// RNN: B=4096, T=1024, H=40, K=41. bf16 I/O, fp32 compute.
// Round-5: kill the LDS-issue bottleneck (round-4: ~300 scalar ds_read/wave/step).
//   - weights row-major, rows padded to 44 floats (176B, 16B-aligned) -> float4 reads
//   - sH/sAct transposed to [el][k] (pad 44/84) -> float4 reads
//   - block = 256 thr / 8 batch elems -> 512 blocks = 2 blocks/CU, 8 waves/CU
//   - same proven 2-barrier schedule and slot assignments as round 4
//   - input softw. prefetch 1 step ahead

#define B_SZ 4096
#define T_SZ 1024
#define HID  40

__device__ __forceinline__ float ldw(const void* p, int i, bool bf) {
  if (bf) {
    unsigned int u = ((unsigned int)((const unsigned short*)p)[i]) << 16;
    union { unsigned int u; float f; } c; c.u = u;
    return c.f;
  }
  return ((const float*)p)[i];
}

__global__ __launch_bounds__(256)
void rnn_kernel(const void* __restrict__ inp,
                const void* __restrict__ h2h_w1, const void* __restrict__ h2h_b1,
                const void* __restrict__ h2h_w2, const void* __restrict__ h2h_b2,
                const void* __restrict__ h2o_w1, const void* __restrict__ h2o_b1,
                const void* __restrict__ h2o_w2, const void* __restrict__ h2o_b2,
                void* __restrict__ out) {
  // Weights, fp32, rows padded to 44 (176B: 16B-aligned, 11 banks offset -> conflict-free)
  __shared__ __align__(16) float sW1h[80][44];  // [j][k] = W1[j][1+k] (hidden part); j<40 h2h, j>=40 h2o
  __shared__ float sW1u[80];                    // W1[j][0] (input weight)
  __shared__ float sB1[80];
  __shared__ __align__(16) float sW2[41][44];   // rows 0..39 = h2h_w2, row 40 = h2o_w2
  __shared__ float sB2[41];                     // [40] = h2o_b2
  __shared__ __align__(16) float sH[8][44];     // [el][k] hidden
  __shared__ __align__(16) float sAct[8][84];   // [el][j] j<40: a-path, j>=40: o-path

  const int tid  = threadIdx.x;
  const int lane = tid & 63;
  const int wv   = tid >> 6;       // 0..3
  const int el   = lane & 7;       // batch elem in tile
  const int sub  = lane >> 3;      // 0..7
  const int slot = wv * 8 + sub;   // 0..31

  // ---- dtype autodetect (uniform; proven round 3) ----
  bool bf = true;
  {
    const unsigned short* p = (const unsigned short*)h2h_w1;
    for (int i = 0; i < 64; ++i) {
      unsigned int u = ((unsigned int)p[i]) << 16;
      union { unsigned int u; float f; } c; c.u = u;
      if (!(fabsf(c.f) <= 0.2f)) bf = false;
    }
  }

  // ---- stage weights (mappings proven rounds 3-4) ----
  for (int idx = tid; idx < 80 * 44; idx += 256) {
    int j = idx / 44, k = idx % 44;
    float v = 0.f;
    if (k < 40)
      v = (j < HID) ? ldw(h2h_w1, j * 41 + 1 + k, bf)
                    : ldw(h2o_w1, (j - HID) * 41 + 1 + k, bf);
    sW1h[j][k] = v;
  }
  for (int j = tid; j < 80; j += 256) {
    sW1u[j] = (j < HID) ? ldw(h2h_w1, j * 41, bf) : ldw(h2o_w1, (j - HID) * 41, bf);
    sB1[j]  = (j < HID) ? ldw(h2h_b1, j, bf)      : ldw(h2o_b1, j - HID, bf);
  }
  for (int idx = tid; idx < 41 * 44; idx += 256) {
    int r = idx / 44, k = idx % 44;
    float v = 0.f;
    if (k < 40) v = (r < HID) ? ldw(h2h_w2, r * HID + k, bf) : ldw(h2o_w2, k, bf);
    sW2[r][k] = v;
  }
  for (int r = tid; r < 41; r += 256)
    sB2[r] = (r < HID) ? ldw(h2h_b2, r, bf) : ldw(h2o_b2, 0, bf);
  for (int idx = tid; idx < 8 * 44; idx += 256)
    ((float*)sH)[idx] = 0.f;
  __syncthreads();

  const int b = blockIdx.x * 8 + el;
  const size_t base = (size_t)b * T_SZ;

  // Phase-A map: slots 0..15 -> 3 neurons {3s..}, 16..31 -> 2 neurons {48+2(s-16)..}
  const int a0 = (slot < 16) ? slot * 3 : 48 + (slot - 16) * 2;
  const int na = (slot < 16) ? 3 : 2;             // uniform per wave (slot<16 <=> wv<2)
  // Phase-B map: slots 0..8 -> rows {2s,2s+1}; slots 9..31 -> row 18+(s-9) (row 40 = output)
  const int r0 = (slot < 9) ? 2 * slot : 18 + (slot - 9);
  const int nr = (slot < 9) ? 2 : 1;
  const int actbase = (slot == 31) ? 40 : 0;      // row-40 slot consumes o-path acts

  float u_cur;
  if (bf) u_cur = ldw(inp, (int)(base + 0), true);
  else    u_cur = ((const float*)inp)[base + 0];

  for (int t = 0; t < T_SZ; ++t) {
    // prefetch next input (independent of LDS phases -> latency hidden)
    float u_nxt = 0.f;
    if (t + 1 < T_SZ) {
      if (bf) u_nxt = ldw(inp, (int)(base + t + 1), true);
      else    u_nxt = ((const float*)inp)[base + t + 1];
    }

    // ---------- Phase A: layer 1 (80 neurons) ----------
    float4 hv[10];
    {
      const float4* hp = (const float4*)sH[el];
#pragma unroll
      for (int i = 0; i < 10; ++i) hv[i] = hp[i];
    }
#pragma unroll
    for (int q = 0; q < 3; ++q) {
      if (q < na) {
        const int j = a0 + q;
        float a = fmaf(u_cur, sW1u[j], sB1[j]);
        const float4* wp = (const float4*)sW1h[j];
#pragma unroll
        for (int i = 0; i < 10; ++i) {
          float4 w = wp[i];
          a = fmaf(hv[i].x, w.x, a);
          a = fmaf(hv[i].y, w.y, a);
          a = fmaf(hv[i].z, w.z, a);
          a = fmaf(hv[i].w, w.w, a);
        }
        a = a > 0.f ? a : 0.01f * a;   // LeakyReLU(0.01)
        sAct[el][j] = a;
      }
    }
    __syncthreads();   // sAct visible; all sH reads done

    // ---------- Phase B: layer 2 (rows 0..39 = hidden, 40 = output) ----------
    float4 av[10];
    {
      const float4* ap = (const float4*)(&sAct[el][actbase]);
#pragma unroll
      for (int i = 0; i < 10; ++i) av[i] = ap[i];
    }
#pragma unroll
    for (int q = 0; q < 2; ++q) {
      if (q < nr) {
        const int r = r0 + q;
        float a = sB2[r];
        const float4* wp = (const float4*)sW2[r];
#pragma unroll
        for (int i = 0; i < 10; ++i) {
          float4 w = wp[i];
          a = fmaf(av[i].x, w.x, a);
          a = fmaf(av[i].y, w.y, a);
          a = fmaf(av[i].z, w.z, a);
          a = fmaf(av[i].w, w.w, a);
        }
        if (r < HID) {
          sH[el][r] = a;
        } else {
          if (bf) ((__hip_bfloat16*)out)[base + t] = __float2bfloat16(a);
          else    ((float*)out)[base + t] = a;
        }
      }
    }
    __syncthreads();   // sH update + sAct reads done before next step

    u_cur = u_nxt;
  }
}

extern "C" void kernel_launch(void* const* d_in, const int* in_sizes, int n_in,
                              void* d_out, int out_size, void* d_ws, size_t ws_size,
                              hipStream_t stream) {
  (void)in_sizes; (void)n_in; (void)out_size; (void)d_ws; (void)ws_size;
  rnn_kernel<<<dim3(B_SZ / 8), dim3(256), 0, stream>>>(
      d_in[0], d_in[1], d_in[2], d_in[3], d_in[4],
      d_in[5], d_in[6], d_in[7], d_in[8], d_out);
}

// Round 8
// 1061.051 us; speedup vs baseline: 262.2492x; 1.9100x over previous
//
#include <hip/hip_runtime.h>
#include <hip/hip_bf16.h>

// RNN: B=4096, T=1024, H=40, K=41. fp32 compute & state.
// Round-8: round-5's proven cooperative schedule + weights resident in VGPRs
// as fp32. Dtype handled by launching BOTH template instantiations; each runs
// the (rounds-3/4/5-proven) autodetect and the non-matching one exits.
//   512 blocks x 256 thr (4 waves), 2 blocks/CU. 8 els/block:
//   el=lane&7, sub=lane>>3, slot=wv*8+sub (0..31).
//   Waves 0-1 (cls1): 3 layer-1 neurons {3s..} + 1 layer-2 row
//       (wv0: rows 32+slot; wv1: slot8 -> row 40 = OUTPUT (o-acts), 9..15 none)
//   Waves 2-3 (cls2): 2 layer-1 neurons {48+2(s-16)..} + 2 layer-2 rows {2(s-16)..}
//   -> uniform 4 weight rows/thread = 160 VGPR, single w4[4][10] array,
//      constant indices only (no dynamic reg addressing -> no spill).
//   LDS: sH + sAct only (~4.6 KB); 2 barriers/step.

#define B_SZ 4096
#define T_SZ 1024
#define HID  40

typedef unsigned short u16;
typedef unsigned int   u32;

__device__ __forceinline__ float bf2f(u16 v) {
  union { u32 u; float f; } c; c.u = ((u32)v) << 16; return c.f;
}

template <bool BF>
__device__ __forceinline__ float ldg(const void* p, long i) {
  if (BF) return bf2f(((const u16*)p)[i]);
  return ((const float*)p)[i];
}

// Proven rounds 3-5: true-bf16 weights all have |w| <= 1/sqrt(41) ~ 0.156;
// fp32 data read as bf16 halfwords exceeds 0.2 with P ~ 1-1e-10.
__device__ __forceinline__ bool detect_bf16(const void* w) {
  const u16* p = (const u16*)w;
  bool bf = true;
  for (int i = 0; i < 64; ++i) {
    float f = bf2f(p[i]);
    if (!(fabsf(f) <= 0.2f)) bf = false;
  }
  return bf;
}

template <bool BF>
__global__ __launch_bounds__(256, 2)
void rnn_kernel(const void* __restrict__ inp,
                const void* __restrict__ h2h_w1, const void* __restrict__ h2h_b1,
                const void* __restrict__ h2h_w2, const void* __restrict__ h2h_b2,
                const void* __restrict__ h2o_w1, const void* __restrict__ h2o_b1,
                const void* __restrict__ h2o_w2, const void* __restrict__ h2o_b2,
                void* __restrict__ out) {
  __shared__ __align__(16) float sH[8][44];    // [el][k]  hidden, stride 176 B
  __shared__ __align__(16) float sAct[8][84];  // [el][j]  j<40 a-path, j>=40 o-path

  if (detect_bf16(h2h_w1) != BF) return;  // wrong-dtype instantiation exits

  const int tid  = threadIdx.x;
  const int lane = tid & 63;
  const int wv   = tid >> 6;      // 0..3
  const int el   = lane & 7;
  const int sub  = lane >> 3;
  const int slot = wv * 8 + sub;  // 0..31
  const bool cls1 = (wv < 2);     // wave-uniform class split

  // Phase-A map (round-5-proven coverage of 80 neurons)
  const int a0 = cls1 ? slot * 3 : 48 + (slot - 16) * 2;
  const int nA = cls1 ? 3 : 2;
  // Phase-B map: cls1 -> one row (32..40 or none); cls2 -> rows 2(s-16), +1
  const int rB = cls1 ? ((slot < 8) ? 32 + slot : ((slot == 8) ? 40 : -1)) : 0;
  const int actbase = (cls1 && slot == 8) ? 40 : 0;  // output row eats o-acts

  // ---- Load this thread's 4 weight rows into registers (fp32) ----
  float4 w4[4][10];
  float  wu[3], ba[3], bb[2];
#pragma unroll
  for (int q = 0; q < 3; ++q) {
    if (q < nA) {
      const int j  = a0 + q;
      const bool hh = (j < HID);
      const void* wb = hh ? h2h_w1 : h2o_w1;
      const long  jr = hh ? j : (j - HID);
      wu[q] = ldg<BF>(wb, jr * 41);
      ba[q] = ldg<BF>(hh ? h2h_b1 : h2o_b1, jr);
#pragma unroll
      for (int i = 0; i < 10; ++i) {
        w4[q][i].x = ldg<BF>(wb, jr * 41 + 1 + 4 * i);
        w4[q][i].y = ldg<BF>(wb, jr * 41 + 2 + 4 * i);
        w4[q][i].z = ldg<BF>(wb, jr * 41 + 3 + 4 * i);
        w4[q][i].w = ldg<BF>(wb, jr * 41 + 4 + 4 * i);
      }
    }
  }
  if (cls1) {
    if (rB >= 0) {
      const bool isout = (rB == 40);
      const void* wb = isout ? h2o_w2 : h2h_w2;
      const long  rr = isout ? 0 : rB;
      bb[0] = isout ? ldg<BF>(h2o_b2, 0) : ldg<BF>(h2h_b2, rB);
#pragma unroll
      for (int i = 0; i < 10; ++i) {
        w4[3][i].x = ldg<BF>(wb, rr * 40 + 4 * i);
        w4[3][i].y = ldg<BF>(wb, rr * 40 + 4 * i + 1);
        w4[3][i].z = ldg<BF>(wb, rr * 40 + 4 * i + 2);
        w4[3][i].w = ldg<BF>(wb, rr * 40 + 4 * i + 3);
      }
    }
  } else {
#pragma unroll
    for (int q = 0; q < 2; ++q) {
      const long r = (slot - 16) * 2 + q;
      bb[q] = ldg<BF>(h2h_b2, r);
#pragma unroll
      for (int i = 0; i < 10; ++i) {
        w4[2 + q][i].x = ldg<BF>(h2h_w2, r * 40 + 4 * i);
        w4[2 + q][i].y = ldg<BF>(h2h_w2, r * 40 + 4 * i + 1);
        w4[2 + q][i].z = ldg<BF>(h2h_w2, r * 40 + 4 * i + 2);
        w4[2 + q][i].w = ldg<BF>(h2h_w2, r * 40 + 4 * i + 3);
      }
    }
  }

  for (int i = tid; i < 8 * 44; i += 256) ((float*)sH)[i] = 0.f;
  __syncthreads();

  const int  b    = blockIdx.x * 8 + el;
  const long base = (long)b * T_SZ;
  float u_cur = ldg<BF>(inp, base);

  for (int t = 0; t < T_SZ; ++t) {
    const float u_nxt = (t + 1 < T_SZ) ? ldg<BF>(inp, base + t + 1) : 0.f;

    // ---------- Phase A: layer 1 ----------
    float4 hv[10];
    {
      const float4* hp = (const float4*)sH[el];
#pragma unroll
      for (int i = 0; i < 10; ++i) hv[i] = hp[i];
    }
#pragma unroll
    for (int q = 0; q < 3; ++q) {
      if (q < nA) {
        float a = fmaf(u_cur, wu[q], ba[q]);
#pragma unroll
        for (int i = 0; i < 10; ++i) {
          a = fmaf(hv[i].x, w4[q][i].x, a);
          a = fmaf(hv[i].y, w4[q][i].y, a);
          a = fmaf(hv[i].z, w4[q][i].z, a);
          a = fmaf(hv[i].w, w4[q][i].w, a);
        }
        a = a > 0.f ? a : 0.01f * a;   // LeakyReLU(0.01)
        sAct[el][a0 + q] = a;
      }
    }
    __syncthreads();   // sAct visible; all sH reads done

    // ---------- Phase B: layer 2 ----------
    if (cls1) {
      if (rB >= 0) {
        const float4* ap = (const float4*)(&sAct[el][actbase]);
        float a2 = bb[0];
#pragma unroll
        for (int i = 0; i < 10; ++i) {
          const float4 a4 = ap[i];
          a2 = fmaf(a4.x, w4[3][i].x, a2);
          a2 = fmaf(a4.y, w4[3][i].y, a2);
          a2 = fmaf(a4.z, w4[3][i].z, a2);
          a2 = fmaf(a4.w, w4[3][i].w, a2);
        }
        if (rB < HID) {
          sH[el][rB] = a2;
        } else {
          if (BF) ((__hip_bfloat16*)out)[base + t] = __float2bfloat16(a2);
          else    ((float*)out)[base + t] = a2;
        }
      }
    } else {
      const float4* ap = (const float4*)(&sAct[el][0]);
      float4 av[10];
#pragma unroll
      for (int i = 0; i < 10; ++i) av[i] = ap[i];
#pragma unroll
      for (int q = 0; q < 2; ++q) {
        const int r = (slot - 16) * 2 + q;
        float a2 = bb[q];
#pragma unroll
        for (int i = 0; i < 10; ++i) {
          a2 = fmaf(av[i].x, w4[2 + q][i].x, a2);
          a2 = fmaf(av[i].y, w4[2 + q][i].y, a2);
          a2 = fmaf(av[i].z, w4[2 + q][i].z, a2);
          a2 = fmaf(av[i].w, w4[2 + q][i].w, a2);
        }
        sH[el][r] = a2;
      }
    }
    __syncthreads();   // sH update + sAct reads done before next step

    u_cur = u_nxt;
  }
}

extern "C" void kernel_launch(void* const* d_in, const int* in_sizes, int n_in,
                              void* d_out, int out_size, void* d_ws, size_t ws_size,
                              hipStream_t stream) {
  (void)in_sizes; (void)n_in; (void)out_size; (void)d_ws; (void)ws_size;
  rnn_kernel<false><<<dim3(B_SZ / 8), dim3(256), 0, stream>>>(
      d_in[0], d_in[1], d_in[2], d_in[3], d_in[4],
      d_in[5], d_in[6], d_in[7], d_in[8], d_out);
  rnn_kernel<true><<<dim3(B_SZ / 8), dim3(256), 0, stream>>>(
      d_in[0], d_in[1], d_in[2], d_in[3], d_in[4],
      d_in[5], d_in[6], d_in[7], d_in[8], d_out);
}